// Round 1
// 180.156 us; speedup vs baseline: 1.0325x; 1.0325x over previous
//
#include <hip/hip_runtime.h>
#include <stdint.h>

// ws layout:
//   [0, 32K)    pid[N]   u32
//   [32K, 64K)  dep[N]   u32 (float depth bits; positive -> monotone as u32)
//   [64K, 96K)  opa[N]   f32 (raw opacity, 0 if culled)
//   [128K, +4M) table[HW] u32 counts — zeroed by us each launch.
//
// Poison-INDEPENDENT design: previous version used the harness 0xAAAAAAAA ws
// poison as the table baseline; during timed graph replay (no re-poison
// between iterations) the baseline drifts and every wave fell into the O(N)
// scan fallback. Explicit 4 MiB zero (~1 us) makes the count==1 fast path
// deterministic on every iteration.

// ---------------------------------------------------------------------------
// Kernel A: project all N gaussians once; bump per-pixel collision counter.
// ---------------------------------------------------------------------------
__global__ __launch_bounds__(256) void gs_project_kernel(
        const float* __restrict__ centers, const float* __restrict__ opac,
        const float* __restrict__ pose, const float* __restrict__ Km,
        const int* __restrict__ Hp, const int* __restrict__ Wp,
        unsigned int* __restrict__ pid_a, unsigned int* __restrict__ dep_a,
        float* __restrict__ opa_a, unsigned int* __restrict__ table, int N) {
    int i = blockIdx.x * blockDim.x + threadIdx.x;
    if (i >= N) return;
    const int H = *Hp, W = *Wp;
    float x = centers[3 * i], y = centers[3 * i + 1], zc = centers[3 * i + 2];
    float cxx = pose[0] * x + pose[1] * y + pose[2]  * zc + pose[3];
    float cyy = pose[4] * x + pose[5] * y + pose[6]  * zc + pose[7];
    float czz = pose[8] * x + pose[9] * y + pose[10] * zc + pose[11];
    bool valid = czz > 0.1f;
    float p0 = Km[0] * cxx + Km[1] * cyy + Km[2] * czz;
    float p1 = Km[3] * cxx + Km[4] * cyy + Km[5] * czz;
    float p2 = Km[6] * cxx + Km[7] * cyy + Km[8] * czz;
    float denom = valid ? p2 : 1.0f;
    int px = (int)(p0 / denom);   // trunc == numpy astype(int32)
    int py = (int)(p1 / denom);
    bool ok = valid && px >= 0 && px < W && py >= 0 && py < H;
    unsigned int pid = ok ? (unsigned int)(py * W + px) : (unsigned int)(H * W);
    pid_a[i] = pid;
    dep_a[i] = __float_as_uint(czz);     // only read when pid matches (ok)
    opa_a[i] = ok ? opac[i] : 0.0f;
    if (ok) atomicAdd(&table[pid], 1u);  // absolute count (table zeroed)
}

// ---------------------------------------------------------------------------
// Kernel B: one wave per gaussian i.
//   count==1 (unique pixel)  -> T=1, direct STORE (sole contributor, out
//                               pre-zeroed; no RMW fetch).   [~99% of waves]
//   count>1                  -> O(N) pid scan (uint4 loads from L2) computing
//     T_i = prod_{j: pid_j==pid_i, (dep_j, j) < (dep_i, i)} (1 - clip(o_j))
//     then atomicAdd (colliders share the pixel).
//   == reference's exclusive transmittance (stable-sort tie-break via index).
// ---------------------------------------------------------------------------
__global__ __launch_bounds__(256) void gs_splat_kernel(
        const unsigned int* __restrict__ pid_a, const unsigned int* __restrict__ dep_a,
        const float* __restrict__ opa_a,
        const unsigned int* __restrict__ table,
        const float* __restrict__ colors, const float* __restrict__ sem,
        float* __restrict__ out, int N, int sem_dim, int HW) {
    const int t = threadIdx.x;
    const int lane = t & 63;
    const int wave = t >> 6;
    const int i = blockIdx.x * 4 + wave;
    if (i >= N) return;

    const unsigned int pid_i = pid_a[i];
    if (pid_i >= (unsigned int)HW) return;   // culled / offscreen
    const float oi = opa_a[i];

    const unsigned int cnt = table[pid_i];   // >=1 (includes self)
    const bool unique = (cnt == 1u);
    float prod = 1.0f;
    if (!unique) {
        const unsigned int di = dep_a[i];
        const uint4* p4 = (const uint4*)pid_a;
        const int nq = N >> 2;
        for (int q = lane; q < nq; q += 64) {
            uint4 p = p4[q];
            int j0 = q << 2;
            #pragma unroll
            for (int k = 0; k < 4; ++k) {
                unsigned int pj = (k == 0) ? p.x : (k == 1) ? p.y : (k == 2) ? p.z : p.w;
                int j = j0 + k;
                if (pj == pid_i && j != i) {
                    unsigned int dj = dep_a[j];
                    if (dj < di || (dj == di && j < i)) {
                        prod *= 1.0f - fminf(fmaxf(opa_a[j], 0.0f), 1.0f - 1e-7f);
                    }
                }
            }
        }
        for (int off = 32; off > 0; off >>= 1) prod *= __shfl_xor(prod, off, 64);
    }

    const float alpha = oi * prod;
    const int fd = 3 + sem_dim;  // 35
    if (lane < fd) {
        float f = (lane < 3) ? colors[3 * i + lane] : sem[sem_dim * i + (lane - 3)];
        float* dst = &out[(size_t)lane * (size_t)HW + pid_i];
        float v = alpha * f;
        if (unique) *dst = v;          // sole contributor: plain store
        else        atomicAdd(dst, v); // colliders accumulate
    }
}

extern "C" void kernel_launch(void* const* d_in, const int* in_sizes, int n_in,
                              void* d_out, int out_size, void* d_ws, size_t ws_size,
                              hipStream_t stream) {
    const float* centers = (const float*)d_in[0];  // (N,3)
    const float* colors  = (const float*)d_in[1];  // (N,3)
    const float* opac    = (const float*)d_in[2];  // (N,1)
    const float* sem     = (const float*)d_in[3];  // (N,SEM_DIM)
    const float* pose    = (const float*)d_in[4];  // (4,4)
    const float* Km      = (const float*)d_in[5];  // (3,3)
    const int*   Hp      = (const int*)d_in[6];
    const int*   Wp      = (const int*)d_in[7];

    int N = in_sizes[0] / 3;        // 8192
    int sem_dim = in_sizes[3] / N;  // 32
    int fd = 3 + sem_dim;           // 35
    int HW = out_size / fd;         // 1024*1024

    char* ws = (char*)d_ws;
    unsigned int* pid_a  = (unsigned int*)(ws);
    unsigned int* dep_a  = (unsigned int*)(ws + 32 * 1024);
    float*        opa_a  = (float*)      (ws + 64 * 1024);
    unsigned int* table  = (unsigned int*)(ws + 128 * 1024);  // HW u32 counts

    // Mandatory 147 MB output zero at the fill ceiling (~22 us @ 6.6 TB/s).
    hipMemsetAsync(d_out, 0, (size_t)out_size * sizeof(float), stream);
    // 4 MiB table zero (~1 us) — buys poison-independence of the fast path.
    hipMemsetAsync(table, 0, (size_t)HW * sizeof(unsigned int), stream);

    gs_project_kernel<<<(N + 255) / 256, 256, 0, stream>>>(
        centers, opac, pose, Km, Hp, Wp, pid_a, dep_a, opa_a, table, N);

    gs_splat_kernel<<<(N + 3) / 4, 256, 0, stream>>>(
        pid_a, dep_a, opa_a, table, colors, sem,
        (float*)d_out, N, sem_dim, HW);
}